// Round 5
// baseline (360.167 us; speedup 1.0000x reference)
//
#include <hip/hip_runtime.h>
#include <hip/hip_bf16.h>

// ModulatedConv2d: out = oscale[b,co] * conv2d(s[b,ci]*x, w_bf16)
// B=8, C=512, K=3, H=W=64.
// Round 5: counted-vmcnt software pipeline (T3+T4). W staged in two rotating
// tap-group LDS regions (S0=taps0..4, S1=taps5..8); x single-buffered,
// rewritten in place each chunk; x(c+2) reg-loads and W(c+1) glls stay in
// flight across barriers (never vmcnt(0) in the loop). T5 setprio on MFMA.

#define CDIM 512
#define HW 64
#define CK 32
#define NCHUNK 16   // 512/32

typedef __attribute__((ext_vector_type(8))) short short8;
typedef __attribute__((ext_vector_type(4))) float float4v;

__device__ __forceinline__ short f2bf(float f) {
    unsigned u = __float_as_uint(f);
    unsigned r = (u + 0x7FFFu + ((u >> 16) & 1u)) >> 16;
    return (short)r;
}

__device__ __forceinline__ void async_ld16(const short* g, short* l) {
    __builtin_amdgcn_global_load_lds(
        (const __attribute__((address_space(1))) void*)g,
        (__attribute__((address_space(3))) void*)l, 16, 0, 0);
}

// ---------------- prep kernels ----------------

__global__ void k_affine(const float* __restrict__ style, const float* __restrict__ aw,
                         const float* __restrict__ ab, float* __restrict__ s) {
    int b = blockIdx.x;
    int ci = blockIdx.y * 256 + threadIdx.x;
    const float* st = style + b * CDIM;
    const float* w = aw + ci * CDIM;
    float acc = 0.f;
    for (int k = 0; k < CDIM; ++k) acc += st[k] * w[k];
    s[b * CDIM + ci] = acc * 0.04419417382415922f + ab[ci];
}

__global__ void k_ws2(const float* __restrict__ w, float* __restrict__ ws2) {
    int i = blockIdx.x * 256 + threadIdx.x;  // 262144
    const float* p = w + i * 9;
    float a = 0.f;
#pragma unroll
    for (int t = 0; t < 9; ++t) a += p[t] * p[t];
    ws2[i] = a;
}

__global__ void k_oscale(const float* __restrict__ s, const float* __restrict__ ws2,
                         float* __restrict__ osc) {
    __shared__ float s2[CDIM];
    int b = blockIdx.x;
    int co = blockIdx.y * 256 + threadIdx.x;
    for (int i = threadIdx.x; i < CDIM; i += 256) {
        float v = s[b * CDIM + i];
        s2[i] = v * v;
    }
    __syncthreads();
    const float* r = ws2 + co * CDIM;
    float acc = 0.f;
    for (int k = 0; k < CDIM; ++k) acc += s2[k] * r[k];
    const float wg = 0.014731391274719739f;          // 1/sqrt(4608)
    const float wg2 = 2.170138888888889e-4f;         // 1/4608
    osc[b * CDIM + co] = wg * rsqrtf(wg2 * acc + 1e-8f);
}

// wgt layout: [chunk16][ct4] regions of 36864 shorts.
// Within region: [t9][mf8][slot64][j8], slot = l4*16 + l15 (lane-linear),
// value = w[co = ct*128 + mf*16 + l15][ci = chunk*32 + l4*8 + j][t]
__global__ void k_wconv(const float* __restrict__ w, short* __restrict__ wgt) {
    int idx = blockIdx.x * 256 + threadIdx.x;  // 2359296
    int j = idx & 7;
    int slotg = idx >> 3;              // global 16B-slot index, 0..294911
    int region = slotg / 4608;         // chunk*4 + ct
    int a16 = slotg - region * 4608;   // 0..4607
    int tm = a16 >> 6;                 // t*8 + mf
    int t = tm >> 3;
    int mf = tm & 7;
    int sl = a16 & 63;
    int l4 = sl >> 4;
    int l15 = sl & 15;
    int ct = region & 3;
    int c = region >> 2;
    int co = ct * 128 + mf * 16 + l15;
    int ci = c * 32 + l4 * 8 + j;
    wgt[idx] = f2bf(w[(co * CDIM + ci) * 9 + t]);
}

// per-tap compute: WL = tap-group LDS base, TBASE = first tap, NT = #taps
#define COMPUTE_TAPS(WL, TBASE, NT)                                             \
    _Pragma("unroll")                                                           \
    for (int tl = 0; tl < (NT); ++tl) {                                         \
        const int t = (TBASE) + tl;                                             \
        const int dh = t / 3 - 1;                                               \
        const int dw = t % 3 - 1;                                               \
        const int lrow = wid + dh + 1;                                          \
        short8 bfr[4];                                                          \
        _Pragma("unroll")                                                       \
        for (int nf = 0; nf < 4; ++nf) {                                        \
            const int lcol = 1 + nf * 16 + l15 + dw;                            \
            const int xq = l4 ^ ((lcol >> 1) & 3);                              \
            bfr[nf] = *(const short8*)&x_lds[(lrow * 66 + lcol) * CK + xq * 8]; \
        }                                                                       \
        _Pragma("unroll")                                                       \
        for (int mf = 0; mf < 8; ++mf) {                                        \
            short8 af = *(const short8*)&(WL)[((tl * 8 + mf) * 64 + lane) * 8]; \
            _Pragma("unroll")                                                   \
            for (int nf = 0; nf < 4; ++nf)                                      \
                acc[mf][nf] = __builtin_amdgcn_mfma_f32_16x16x32_bf16(          \
                    af, bfr[nf], acc[mf][nf], 0, 0, 0);                         \
        }                                                                       \
    }

// ---------------- main conv ----------------
// grid 256 blocks x 512 threads. Block: (ct co-tile of 128, b, row-tile of 8).
__global__ __launch_bounds__(512, 1) void conv_main(
    const float* __restrict__ x, const float* __restrict__ s,
    const short* __restrict__ wgt, const float* __restrict__ osc,
    float* __restrict__ out) {

    __shared__ __align__(16) short s0_lds[5 * 8 * 64 * 8];   // 40960 B (taps 0..4)
    __shared__ __align__(16) short s1_lds[4 * 8 * 64 * 8];   // 32768 B (taps 5..8)
    __shared__ __align__(16) short x_lds[10 * 66 * CK];      // 42240 B

    const int tid = threadIdx.x;
    const int lane = tid & 63;
    const int wid = tid >> 6;          // 0..7 = output row within tile
    const int l15 = lane & 15;
    const int l4 = lane >> 4;

    // XCD-aware mapping: b == xcd; 4 ct-blocks of one (b,rt) share the x slice.
    const int bx = blockIdx.x;
    const int xcd = bx & 7;
    const int t7 = bx >> 3;            // 0..31
    const int ct = t7 & 3;
    const int ghi = t7 >> 2;           // 0..7
    const int b = xcd;
    const int r0 = ghi * 8;

    // staging lane mapping: 4 cig x 64 col x 2 rowhalf
    const int cig = tid & 3;               // ci 8-block
    const int col = (tid >> 2) & 63;
    const int rowhalf = tid >> 8;          // 0/1

    // zero halo columns (lcol 0 and 65), once
    for (int i = tid; i < 320; i += 512) {
        int row = i >> 5;
        int w16 = i & 31;
        int colh = (w16 >= 16) ? 65 : 0;
        int q16 = w16 & 15;
        ((unsigned*)x_lds)[(row * 66 + colh) * 16 + q16] = 0u;
    }

    float rx[40];
    float4v sva, svb;

    auto stage_w0 = [&](int c) {   // taps 0..4 -> S0 : 5 glls/wave
        const short* src = wgt + (c * 4 + ct) * 36864;
#pragma unroll
        for (int k = 0; k < 5; ++k) {
            int off = (k * 512 + wid * 64) * 8;
            async_ld16(src + off + lane * 8, s0_lds + off);
        }
    };
    auto stage_w1 = [&](int c) {   // taps 5..8 -> S1 : 4 glls/wave
        const short* src = wgt + (c * 4 + ct) * 36864 + 5 * 512 * 8;
#pragma unroll
        for (int k = 0; k < 4; ++k) {
            int off = (k * 512 + wid * 64) * 8;
            async_ld16(src + off + lane * 8, s1_lds + off);
        }
    };

    auto stage_x_load = [&](int c) {   // 42 VMEM/wave (2 s + 40 x)
        const float4v* sp = (const float4v*)&s[b * CDIM + c * 32 + cig * 8];
        sva = sp[0]; svb = sp[1];
#pragma unroll
        for (int i = 0; i < 5; ++i) {
            int row = 2 * i + rowhalf;         // 0..9
            int grow = r0 - 1 + row;
            bool ok = (grow >= 0) && (grow < HW);
            const float* base = x + ((b * CDIM + c * 32 + cig * 8) * HW + (ok ? grow : 0)) * HW + col;
#pragma unroll
            for (int j = 0; j < 8; ++j) {
                float v = base[j * (HW * HW)];
                rx[i * 8 + j] = ok ? v : 0.0f;
            }
        }
    };

    auto stage_x_write = [&]() {
        int lcol = col + 1;
        int q = cig ^ ((lcol >> 1) & 3);
#pragma unroll
        for (int i = 0; i < 5; ++i) {
            int row = 2 * i + rowhalf;
            short8 pk;
#pragma unroll
            for (int j = 0; j < 8; ++j) {
                float sj = (j < 4) ? sva[j] : svb[j - 4];
                pk[j] = f2bf(rx[i * 8 + j] * sj);
            }
            *(short8*)&x_lds[(row * 66 + lcol) * CK + q * 8] = pk;
        }
    };

    float4v acc[8][4] = {};

    // ---- prologue: stage W(0), x(0); preload x(1); full drain once ----
    stage_w0(0);
    stage_w1(0);
    stage_x_load(0);
    stage_x_write();                 // compiler inserts the vmcnt wait for rx
    stage_x_load(1);
    __builtin_amdgcn_sched_barrier(0);
    asm volatile("s_waitcnt vmcnt(42) lgkmcnt(0)" ::: "memory");  // glls drained, x(1) in flight
    __builtin_amdgcn_sched_barrier(0);
    __builtin_amdgcn_s_barrier();
    __builtin_amdgcn_sched_barrier(0);

#pragma unroll 1
    for (int c = 0; c < NCHUNK; ++c) {
        // entry: S0=T0(c), S1=T1(c), x_lds=x(c) all published; rx=x(c+1) in flight
        __builtin_amdgcn_s_setprio(1);
        COMPUTE_TAPS(s0_lds, 0, 5)
        __builtin_amdgcn_s_setprio(0);

        // B: own T1(c) done (outstanding: [T1(c) 4][x(c+1) 42] -> wait <=42)
        __builtin_amdgcn_sched_barrier(0);
        asm volatile("s_waitcnt vmcnt(42) lgkmcnt(0)" ::: "memory");
        __builtin_amdgcn_sched_barrier(0);
        __builtin_amdgcn_s_barrier();      // publishes T1(c); all done reading S0
        __builtin_amdgcn_sched_barrier(0);

        const int cc1 = (c + 1 < NCHUNK) ? c + 1 : NCHUNK - 1;
        stage_w0(cc1);                     // 5 glls -> S0 (safe: S0 readers done)
        __builtin_amdgcn_sched_barrier(0);

        __builtin_amdgcn_s_setprio(1);
        COMPUTE_TAPS(s1_lds, 5, 4)
        __builtin_amdgcn_s_setprio(0);

        // C: all waves done reading S1 and x_lds
        __builtin_amdgcn_sched_barrier(0);
        asm volatile("s_waitcnt lgkmcnt(0)" ::: "memory");
        __builtin_amdgcn_s_barrier();
        __builtin_amdgcn_sched_barrier(0);

        stage_w1(cc1);                     // 4 glls -> S1
        __builtin_amdgcn_sched_barrier(0);
        stage_x_write();                   // rx=x(c+1) -> x_lds (compiler waits rx)
        const int cc2 = (c + 2 < NCHUNK) ? c + 2 : NCHUNK - 1;
        stage_x_load(cc2);                 // 42 loads -> rx
        __builtin_amdgcn_sched_barrier(0);

        // D: own T0(c+1) done (outstanding: [T0 5][T1 4][x 42] -> wait <=46);
        // lgkm(0) makes x ds_writes visible. x(c+2)+T1(c+1) stay in flight.
        asm volatile("s_waitcnt vmcnt(46) lgkmcnt(0)" ::: "memory");
        __builtin_amdgcn_sched_barrier(0);
        __builtin_amdgcn_s_barrier();      // publishes S0=T0(c+1), x_lds=x(c+1)
        __builtin_amdgcn_sched_barrier(0);
    }

    // epilogue: demodulate + store
    const int row_out = r0 + wid;
#pragma unroll
    for (int mf = 0; mf < 8; ++mf) {
        float4v ov = *(const float4v*)&osc[b * CDIM + ct * 128 + mf * 16 + l4 * 4];
#pragma unroll
        for (int j = 0; j < 4; ++j) {
            int co = ct * 128 + mf * 16 + l4 * 4 + j;
            float* po = out + ((b * CDIM + co) * HW + row_out) * HW;
#pragma unroll
            for (int nf = 0; nf < 4; ++nf)
                po[nf * 16 + l15] = acc[mf][nf][j] * ov[j];
        }
    }
}

// ---------------- launcher ----------------

extern "C" void kernel_launch(void* const* d_in, const int* in_sizes, int n_in,
                              void* d_out, int out_size, void* d_ws, size_t ws_size,
                              hipStream_t stream) {
    const float* x     = (const float*)d_in[0];   // 8*512*64*64
    const float* style = (const float*)d_in[1];   // 8*512
    const float* w     = (const float*)d_in[2];   // 512*512*9
    const float* aw    = (const float*)d_in[3];   // 512*512
    const float* ab    = (const float*)d_in[4];   // 512
    float* out = (float*)d_out;

    float* s_buf = (float*)d_ws;                 // 4096
    float* ws2   = s_buf + 4096;                 // 262144
    float* osc   = ws2 + 262144;                 // 4096
    short* wgt   = (short*)(osc + 4096);         // 2359296 shorts (~4.5 MB)

    k_affine<<<dim3(8, 2), 256, 0, stream>>>(style, aw, ab, s_buf);
    k_ws2<<<1024, 256, 0, stream>>>(w, ws2);
    k_wconv<<<9216, 256, 0, stream>>>(w, wgt);
    k_oscale<<<dim3(8, 2), 256, 0, stream>>>(s_buf, ws2, osc);
    conv_main<<<256, 512, 0, stream>>>(x, s_buf, wgt, osc, out);
}

// Round 6
// 185.610 us; speedup vs baseline: 1.9405x; 1.9405x over previous
//
#include <hip/hip_runtime.h>
#include <hip/hip_bf16.h>

// ModulatedConv2d: out = oscale[b,co] * conv2d(s[b,ci]*x, w_bf16)
// B=8, C=512, K=3, H=W=64.
// Round 6: precompute xs = bf16(s*x) in LDS-image (pre-swizzled) layout; conv
// stages BOTH operands via global_load_lds only (no reg staging, no in-loop
// VALU). x double-buffered, W single-buffered; one counted vmcnt(5) per chunk
// (x prefetch stays in flight), two barriers. Fallback to round-4 kernel if
// ws_size too small.

#define CDIM 512
#define HW 64
#define CK 32
#define NCHUNK 16   // 512/32

typedef __attribute__((ext_vector_type(8))) short short8;
typedef __attribute__((ext_vector_type(4))) float float4v;

__device__ __forceinline__ short f2bf(float f) {
    unsigned u = __float_as_uint(f);
    unsigned r = (u + 0x7FFFu + ((u >> 16) & 1u)) >> 16;
    return (short)r;
}

__device__ __forceinline__ void async_ld16(const short* g, short* l) {
    __builtin_amdgcn_global_load_lds(
        (const __attribute__((address_space(1))) void*)g,
        (__attribute__((address_space(3))) void*)l, 16, 0, 0);
}

__device__ __forceinline__ void hard_sync() {
    asm volatile("s_waitcnt vmcnt(0) lgkmcnt(0)" ::: "memory");
    __builtin_amdgcn_sched_barrier(0);
    __builtin_amdgcn_s_barrier();
    __builtin_amdgcn_sched_barrier(0);
}

// ---------------- prep kernels ----------------

__global__ void k_affine(const float* __restrict__ style, const float* __restrict__ aw,
                         const float* __restrict__ ab, float* __restrict__ s) {
    int b = blockIdx.x;
    int ci = blockIdx.y * 256 + threadIdx.x;
    const float* st = style + b * CDIM;
    const float* w = aw + ci * CDIM;
    float acc = 0.f;
    for (int k = 0; k < CDIM; ++k) acc += st[k] * w[k];
    s[b * CDIM + ci] = acc * 0.04419417382415922f + ab[ci];
}

__global__ void k_ws2(const float* __restrict__ w, float* __restrict__ ws2) {
    int i = blockIdx.x * 256 + threadIdx.x;  // 262144
    const float* p = w + i * 9;
    float a = 0.f;
#pragma unroll
    for (int t = 0; t < 9; ++t) a += p[t] * p[t];
    ws2[i] = a;
}

__global__ void k_oscale(const float* __restrict__ s, const float* __restrict__ ws2,
                         float* __restrict__ osc) {
    __shared__ float s2[CDIM];
    int b = blockIdx.x;
    int co = blockIdx.y * 256 + threadIdx.x;
    for (int i = threadIdx.x; i < CDIM; i += 256) {
        float v = s[b * CDIM + i];
        s2[i] = v * v;
    }
    __syncthreads();
    const float* r = ws2 + co * CDIM;
    float acc = 0.f;
    for (int k = 0; k < CDIM; ++k) acc += s2[k] * r[k];
    const float wg = 0.014731391274719739f;          // 1/sqrt(4608)
    const float wg2 = 2.170138888888889e-4f;         // 1/4608
    osc[b * CDIM + co] = wg * rsqrtf(wg2 * acc + 1e-8f);
}

// wgt layout: [chunk16][ct4] regions of 36864 shorts.
// Within region: [t9][mf8][slot64][j8], slot = l4*16 + l15 (lane-linear),
// value = w[co = ct*128 + mf*16 + l15][ci = chunk*32 + l4*8 + j][t]
__global__ void k_wconv(const float* __restrict__ w, short* __restrict__ wgt) {
    int idx = blockIdx.x * 256 + threadIdx.x;  // 2359296
    int j = idx & 7;
    int slotg = idx >> 3;
    int region = slotg / 4608;         // chunk*4 + ct
    int a16 = slotg - region * 4608;
    int tm = a16 >> 6;                 // t*8 + mf
    int t = tm >> 3;
    int mf = tm & 7;
    int sl = a16 & 63;
    int l4 = sl >> 4;
    int l15 = sl & 15;
    int ct = region & 3;
    int c = region >> 2;
    int co = ct * 128 + mf * 16 + l15;
    int ci = c * 32 + l4 * 8 + j;
    wgt[idx] = f2bf(w[(co * CDIM + ci) * 9 + t]);
}

// xs layout: [b8][c16][grow64] rows of 2048 shorts, each row = the LDS interior
// image (lcol 1..64): offset o = (lcol-1)*32 + q*8 + j holds
// bf16( x[b][ci][grow][lcol-1] * s[b][ci] ), ci = c*32 + (q ^ ((lcol>>1)&3))*8 + j.
__global__ void k_xs(const float* __restrict__ x, const float* __restrict__ s,
                     short* __restrict__ xs) {
    const int bx = blockIdx.x;         // (b*16 + c)*64 + grow
    const int grow = bx & 63;
    const int t = bx >> 6;
    const int c = t & 15;
    const int b = t >> 4;
    const int q = threadIdx.x >> 6;    // 0..3
    const int lane = threadIdx.x & 63; // gcol; lcol = lane+1
    const int cig = q ^ (((lane + 1) >> 1) & 3);
    const int ci0 = c * 32 + cig * 8;
    const float* xb = x + ((b * CDIM + ci0) * HW + grow) * HW + lane;
    const float* sb = s + b * CDIM + ci0;
    short8 pk;
#pragma unroll
    for (int j = 0; j < 8; ++j)
        pk[j] = f2bf(xb[j * (HW * HW)] * sb[j]);
    *(short8*)&xs[bx * 2048 + lane * 32 + q * 8] = pk;
}

// ---------------- main conv (v2: pure-gll staging) ----------------
// grid 256 blocks x 512 threads. Block: (ct co-tile of 128, b, row-tile of 8).
__global__ __launch_bounds__(512, 1) void conv_main2(
    const short* __restrict__ xs, const short* __restrict__ zs,
    const short* __restrict__ wgt, const float* __restrict__ osc,
    float* __restrict__ out) {

    __shared__ __align__(16) short w_lds[9 * 8 * 64 * 8];    // 73728 B
    __shared__ __align__(16) short x_lds[2][10 * 66 * CK];   // 2*42240 B

    const int tid = threadIdx.x;
    const int lane = tid & 63;
    const int wid = tid >> 6;          // 0..7
    const int l15 = lane & 15;
    const int l4 = lane >> 4;

    // b == xcd; the 4 ct-blocks of one (b,rt) group share the xs slice in L2.
    const int bx = blockIdx.x;
    const int xcd = bx & 7;
    const int t7 = bx >> 3;
    const int ct = t7 & 3;
    const int ghi = t7 >> 2;           // 0..7
    const int b = xcd;
    const int r0 = ghi * 8;

    // zero halo columns (lcol 0 and 65) of both buffers, once
    for (int i = tid; i < 640; i += 512) {
        int bufi = i >= 320;
        int v = i - bufi * 320;
        int row = v >> 5;
        int w16 = v & 31;
        int colh = (w16 >= 16) ? 65 : 0;
        int q16 = w16 & 15;
        ((unsigned*)x_lds[bufi])[(row * 66 + colh) * 16 + q16] = 0u;
    }

    auto stage_w = [&](int c) {   // 9 glls/wave
        const short* src = wgt + (c * 4 + ct) * 36864;
#pragma unroll
        for (int k = 0; k < 9; ++k) {
            int off = (k * 512 + wid * 64) * 8;
            async_ld16(src + off + lane * 8, w_lds + off);
        }
    };

    auto stage_x = [&](int c, int buf) {   // 5 glls/wave, uniform (zs redirect)
        const short* xsb = xs + ((b * 16 + c) << 17);   // 64 rows * 2048
#pragma unroll
        for (int k = 0; k < 5; ++k) {
            int slot = wid * 5 + k;     // 0..39
            int row = slot >> 2;        // 0..9
            int part = slot & 3;
            int grow = r0 - 1 + row;
            const short* src = (grow >= 0 && grow < HW)
                ? xsb + grow * 2048 + part * 512
                : zs + part * 512;
            short* dst = &x_lds[buf][(row * 66 + 1) * CK] + part * 512;
            async_ld16(src + lane * 8, dst + lane * 8);
        }
    };

    float4v acc[8][4] = {};

    auto compute = [&](int buf) {
        const short* xb = x_lds[buf];
#pragma unroll
        for (int t = 0; t < 9; ++t) {
            int dh = t / 3 - 1;
            int dw = t % 3 - 1;
            int lrow = wid + dh + 1;   // 0..9
            short8 bfr[4];
#pragma unroll
            for (int nf = 0; nf < 4; ++nf) {
                int lcol = 1 + nf * 16 + l15 + dw;
                int xq = l4 ^ ((lcol >> 1) & 3);
                bfr[nf] = *(const short8*)&xb[(lrow * 66 + lcol) * CK + xq * 8];
            }
#pragma unroll
            for (int mf = 0; mf < 8; ++mf) {
                short8 af = *(const short8*)&w_lds[((t * 8 + mf) * 64 + lane) * 8];
#pragma unroll
                for (int nf = 0; nf < 4; ++nf)
                    acc[mf][nf] = __builtin_amdgcn_mfma_f32_16x16x32_bf16(
                        af, bfr[nf], acc[mf][nf], 0, 0, 0);
            }
        }
    };

    // prologue: W(0), x(0)->buf0, x(1)->buf1; drain all but x(1)'s 5 glls
    stage_w(0);
    stage_x(0, 0);
    stage_x(1, 1);
    __builtin_amdgcn_sched_barrier(0);
    asm volatile("s_waitcnt vmcnt(5) lgkmcnt(0)" ::: "memory");
    __builtin_amdgcn_sched_barrier(0);
    __builtin_amdgcn_s_barrier();
    __builtin_amdgcn_sched_barrier(0);

    int cur = 0;
#pragma unroll 1
    for (int c = 0; c < NCHUNK; ++c) {
        // invariant: w_lds=W(c), x_lds[cur]=x(c) published; x(c+1) 5 glls in flight
        __builtin_amdgcn_s_setprio(1);
        compute(cur);
        __builtin_amdgcn_s_setprio(0);

        // all waves done reading w_lds and x_lds[cur]
        __builtin_amdgcn_sched_barrier(0);
        asm volatile("s_waitcnt lgkmcnt(0)" ::: "memory");
        __builtin_amdgcn_s_barrier();
        __builtin_amdgcn_sched_barrier(0);

        const int cc1 = (c + 1 < NCHUNK) ? c + 1 : NCHUNK - 1;
        const int cc2 = (c + 2 < NCHUNK) ? c + 2 : NCHUNK - 1;
        stage_w(cc1);            // 9 glls -> w_lds
        stage_x(cc2, cur);       // 5 glls -> x_lds[cur] (just-read buffer)
        __builtin_amdgcn_sched_barrier(0);

        // drain x(c+1)[5] + W(c+1)[9]; leave x(c+2)[5] in flight
        asm volatile("s_waitcnt vmcnt(5)" ::: "memory");
        __builtin_amdgcn_sched_barrier(0);
        __builtin_amdgcn_s_barrier();      // publish W(c+1), x_lds[cur^1]=x(c+1)
        __builtin_amdgcn_sched_barrier(0);
        cur ^= 1;
    }

    // epilogue: demodulate + store
    const int row_out = r0 + wid;
#pragma unroll
    for (int mf = 0; mf < 8; ++mf) {
        float4v ov = *(const float4v*)&osc[b * CDIM + ct * 128 + mf * 16 + l4 * 4];
#pragma unroll
        for (int j = 0; j < 4; ++j) {
            int co = ct * 128 + mf * 16 + l4 * 4 + j;
            float* po = out + ((b * CDIM + co) * HW + row_out) * HW;
#pragma unroll
            for (int nf = 0; nf < 4; ++nf)
                po[nf * 16 + l15] = acc[mf][nf][j] * ov[j];
        }
    }
}

// ---------------- fallback conv (round-4 proven, reg-staged x) ----------------
__global__ __launch_bounds__(512, 1) void conv_main_fb(
    const float* __restrict__ x, const float* __restrict__ s,
    const short* __restrict__ wgt, const float* __restrict__ osc,
    float* __restrict__ out) {

    __shared__ __align__(16) short w_lds[9 * 8 * 64 * 8];
    __shared__ __align__(16) short x_lds[2][10 * 66 * CK];

    const int tid = threadIdx.x;
    const int lane = tid & 63;
    const int wid = tid >> 6;
    const int l15 = lane & 15;
    const int l4 = lane >> 4;

    const int bx = blockIdx.x;
    const int xcd = bx & 7;
    const int t7 = bx >> 3;
    const int ct = t7 & 3;
    const int ghi = t7 >> 2;
    const int b = xcd;
    const int r0 = ghi * 8;

    const int cig = tid & 3;
    const int col = (tid >> 2) & 63;
    const int rowhalf = tid >> 8;

    for (int i = tid; i < 640; i += 512) {
        int bufi = i >= 320;
        int v = i - bufi * 320;
        int row = v >> 5;
        int w16 = v & 31;
        int colh = (w16 >= 16) ? 65 : 0;
        int q16 = w16 & 15;
        ((unsigned*)x_lds[bufi])[(row * 66 + colh) * 16 + q16] = 0u;
    }

    float rx[40];
    float4v sva, svb;

    auto stage_w = [&](int c) {
        const short* src = wgt + (c * 4 + ct) * 36864;
#pragma unroll
        for (int k = 0; k < 9; ++k) {
            int off = (k * 512 + wid * 64) * 8;
            async_ld16(src + off + lane * 8, w_lds + off);
        }
    };

    auto stage_x_load = [&](int c) {
        const float4v* sp = (const float4v*)&s[b * CDIM + c * 32 + cig * 8];
        sva = sp[0]; svb = sp[1];
#pragma unroll
        for (int i = 0; i < 5; ++i) {
            int row = 2 * i + rowhalf;
            int grow = r0 - 1 + row;
            bool ok = (grow >= 0) && (grow < HW);
            const float* base = x + ((b * CDIM + c * 32 + cig * 8) * HW + (ok ? grow : 0)) * HW + col;
#pragma unroll
            for (int j = 0; j < 8; ++j) {
                float v = base[j * (HW * HW)];
                rx[i * 8 + j] = ok ? v : 0.0f;
            }
        }
    };

    auto stage_x_write = [&](int buf) {
        int lcol = col + 1;
        int q = cig ^ ((lcol >> 1) & 3);
#pragma unroll
        for (int i = 0; i < 5; ++i) {
            int row = 2 * i + rowhalf;
            short8 pk;
#pragma unroll
            for (int j = 0; j < 8; ++j) {
                float sj = (j < 4) ? sva[j] : svb[j - 4];
                pk[j] = f2bf(rx[i * 8 + j] * sj);
            }
            *(short8*)&x_lds[buf][(row * 66 + lcol) * CK + q * 8] = pk;
        }
    };

    float4v acc[8][4] = {};

    auto compute = [&](int buf) {
        const short* xb = x_lds[buf];
#pragma unroll
        for (int t = 0; t < 9; ++t) {
            int dh = t / 3 - 1;
            int dw = t % 3 - 1;
            int lrow = wid + dh + 1;
            short8 bfr[4];
#pragma unroll
            for (int nf = 0; nf < 4; ++nf) {
                int lcol = 1 + nf * 16 + l15 + dw;
                int xq = l4 ^ ((lcol >> 1) & 3);
                bfr[nf] = *(const short8*)&xb[(lrow * 66 + lcol) * CK + xq * 8];
            }
#pragma unroll
            for (int mf = 0; mf < 8; ++mf) {
                short8 af = *(const short8*)&w_lds[((t * 8 + mf) * 64 + lane) * 8];
#pragma unroll
                for (int nf = 0; nf < 4; ++nf)
                    acc[mf][nf] = __builtin_amdgcn_mfma_f32_16x16x32_bf16(
                        af, bfr[nf], acc[mf][nf], 0, 0, 0);
            }
        }
    };

    stage_w(0);
    stage_x_load(0);
    stage_x_write(0);
    hard_sync();

    int cur = 0;
#pragma unroll 1
    for (int c = 0; c < NCHUNK; ++c) {
        if (c + 1 < NCHUNK) stage_x_load(c + 1);
        compute(cur);
        if (c + 1 < NCHUNK) {
            hard_sync();
            stage_w(c + 1);
            stage_x_write(cur ^ 1);
            hard_sync();
            cur ^= 1;
        }
    }

    const int row_out = r0 + wid;
#pragma unroll
    for (int mf = 0; mf < 8; ++mf) {
        float4v ov = *(const float4v*)&osc[b * CDIM + ct * 128 + mf * 16 + l4 * 4];
#pragma unroll
        for (int j = 0; j < 4; ++j) {
            int co = ct * 128 + mf * 16 + l4 * 4 + j;
            float* po = out + ((b * CDIM + co) * HW + row_out) * HW;
#pragma unroll
            for (int nf = 0; nf < 4; ++nf)
                po[nf * 16 + l15] = acc[mf][nf][j] * ov[j];
        }
    }
}

// ---------------- launcher ----------------

extern "C" void kernel_launch(void* const* d_in, const int* in_sizes, int n_in,
                              void* d_out, int out_size, void* d_ws, size_t ws_size,
                              hipStream_t stream) {
    const float* x     = (const float*)d_in[0];   // 8*512*64*64
    const float* style = (const float*)d_in[1];   // 8*512
    const float* w     = (const float*)d_in[2];   // 512*512*9
    const float* aw    = (const float*)d_in[3];   // 512*512
    const float* ab    = (const float*)d_in[4];   // 512
    float* out = (float*)d_out;

    char* wsb = (char*)d_ws;
    float* s_buf = (float*)(wsb);                 // 16384 B
    float* ws2   = (float*)(wsb + 16384);         // 1048576 B
    float* osc   = (float*)(wsb + 1064960);       // 16384 B
    short* wgt   = (short*)(wsb + 1081344);       // 4718592 B
    short* zs    = (short*)(wsb + 5799936);       // 4096 B (zero page)
    short* xs    = (short*)(wsb + 5804032);       // 33554432 B
    const size_t need = 5804032ull + 33554432ull;

    k_affine<<<dim3(8, 2), 256, 0, stream>>>(style, aw, ab, s_buf);
    k_ws2<<<1024, 256, 0, stream>>>(w, ws2);
    k_wconv<<<9216, 256, 0, stream>>>(w, wgt);
    k_oscale<<<dim3(8, 2), 256, 0, stream>>>(s_buf, ws2, osc);

    if (ws_size >= need) {
        hipMemsetAsync(zs, 0, 4096, stream);
        k_xs<<<8192, 256, 0, stream>>>(x, s_buf, xs);
        conv_main2<<<256, 512, 0, stream>>>(xs, zs, wgt, osc, out);
    } else {
        conv_main_fb<<<256, 512, 0, stream>>>(x, s_buf, wgt, osc, out);
    }
}